// Round 1
// baseline (933.614 us; speedup 1.0000x reference)
//
#include <hip/hip_runtime.h>

static constexpr int F = 128;
static constexpr int N_RBF = 20;
static constexpr int N_ATOMS = 8000;
static constexpr int N_EDGES = 160000;
static constexpr int N_MOLS = 100;
static constexpr float CUTOFF = 5.0f;
#define PIF 3.14159265358979323846f

__device__ __forceinline__ float silu_f(float x) { return x / (1.f + __expf(-x)); }

// ---------------- edge geometry: d, unit, rbf*env, env ----------------
__global__ __launch_bounds__(256) void geom_kernel(
    const float* __restrict__ xyz, const int* __restrict__ nbrs,
    float* __restrict__ rbfe, float* __restrict__ envb, float* __restrict__ unitb)
{
    int e = blockIdx.x * 256 + threadIdx.x;
    if (e >= N_EDGES) return;
    int i0 = nbrs[2*e+0], i1 = nbrs[2*e+1];
    float dx = xyz[3*i1+0] - xyz[3*i0+0];
    float dy = xyz[3*i1+1] - xyz[3*i0+1];
    float dz = xyz[3*i1+2] - xyz[3*i0+2];
    float d  = sqrtf(dx*dx + dy*dy + dz*dz);
    float inv = 1.f / d;
    unitb[3*e+0] = dx*inv; unitb[3*e+1] = dy*inv; unitb[3*e+2] = dz*inv;
    float ev = (d <= CUTOFF) ? 0.5f*(cosf(PIF*d/CUTOFF) + 1.f) : 0.f;
    envb[e] = ev;
    float base = PIF*d/CUTOFF;
    float sc = inv * ev;   // fold env into rbf (w_s = (rbf*env)@W + b*env)
    #pragma unroll
    for (int k = 0; k < N_RBF; ++k)
        rbfe[e*N_RBF + k] = sinf((float)(k+1)*base) * sc;
}

// ---------------- s = emb_table[z] ----------------
__global__ __launch_bounds__(256) void embed_kernel(
    const float* __restrict__ emb, const int* __restrict__ z, float* __restrict__ s)
{
    int idx = blockIdx.x * 256 + threadIdx.x;   // grid sized exactly N*F
    int n = idx >> 7, f = idx & 127;
    s[idx] = emb[z[n]*F + f];
}

// ---------------- generic f32 GEMM: C = act(A@B + bias) ----------------
// A: MxK row-major, B: KxNc row-major. M%64==0, Nc%64==0, K%16==0 (guaranteed here).
__global__ __launch_bounds__(256) void gemm_bias_act(
    const float* __restrict__ A, const float* __restrict__ B,
    const float* __restrict__ bias, float* __restrict__ C,
    int M, int K, int Nc, int act)
{
    __shared__ float As[16][68];   // [k][m], padded row => 16B-aligned float4 reads
    __shared__ float Bs[16][64];   // [k][n]
    const int tid = threadIdx.x;
    const int tx = tid & 15, ty = tid >> 4;
    const int m0 = blockIdx.y * 64, n0 = blockIdx.x * 64;
    float acc[4][4] = {};
    const int ka = tid & 15;
    const int ma = tid >> 4;
    const int kb = tid >> 4;
    const int cb = (tid & 15) * 4;
    for (int k0 = 0; k0 < K; k0 += 16) {
        #pragma unroll
        for (int r = 0; r < 4; ++r)
            As[ka][ma + 16*r] = A[(size_t)(m0 + ma + 16*r) * K + k0 + ka];
        *(float4*)&Bs[kb][cb] = *(const float4*)&B[(size_t)(k0 + kb) * Nc + n0 + cb];
        __syncthreads();
        #pragma unroll
        for (int kk = 0; kk < 16; ++kk) {
            float4 av = *(const float4*)&As[kk][ty*4];
            float4 bv = *(const float4*)&Bs[kk][tx*4];
            float aa[4] = {av.x, av.y, av.z, av.w};
            float bb[4] = {bv.x, bv.y, bv.z, bv.w};
            #pragma unroll
            for (int i = 0; i < 4; ++i)
                #pragma unroll
                for (int j = 0; j < 4; ++j)
                    acc[i][j] += aa[i] * bb[j];
        }
        __syncthreads();
    }
    float bcol[4];
    #pragma unroll
    for (int j = 0; j < 4; ++j) bcol[j] = bias ? bias[n0 + tx*4 + j] : 0.f;
    #pragma unroll
    for (int i = 0; i < 4; ++i) {
        float4 o;
        o.x = acc[i][0] + bcol[0];
        o.y = acc[i][1] + bcol[1];
        o.z = acc[i][2] + bcol[2];
        o.w = acc[i][3] + bcol[3];
        if (act) { o.x = silu_f(o.x); o.y = silu_f(o.y); o.z = silu_f(o.z); o.w = silu_f(o.w); }
        *(float4*)&C[(size_t)(m0 + ty*4 + i) * Nc + n0 + tx*4] = o;
    }
}

// ---------------- edge message: w_s, inv, scatter to s and dv ----------------
// One 128-thread block walks edges grid-stride; rbf_w slice (20x384, 30 KB) in LDS.
// Reads OLD v (frozen); accumulates dv separately (ref gathers v before update).
__global__ __launch_bounds__(128) void msg_kernel(
    const float* __restrict__ phi, const float* __restrict__ rbfe,
    const float* __restrict__ envb, const float* __restrict__ unitb,
    const int* __restrict__ nbrs, const float* __restrict__ rbf_w,
    const float* __restrict__ rbf_b, const float* __restrict__ v,
    float* __restrict__ s, float* __restrict__ dv)
{
    __shared__ float Wl[N_RBF * 3 * F];
    __shared__ float bl[3 * F];
    const int tid = threadIdx.x;
    for (int idx = tid; idx < N_RBF * 3 * F; idx += 128) Wl[idx] = rbf_w[idx];
    for (int idx = tid; idx < 3 * F; idx += 128) bl[idx] = rbf_b[idx];
    __syncthreads();
    const size_t NF = (size_t)N_ATOMS * F;
    const float b0 = bl[tid], b1 = bl[tid + F], b2 = bl[tid + 2*F];
    for (int e = blockIdx.x; e < N_EDGES; e += gridDim.x) {
        float ev = envb[e];
        if (ev == 0.f) continue;           // dead edge (d > cutoff): all contributions 0
        int tgt = nbrs[2*e+0], j = nbrs[2*e+1];
        float ux = unitb[3*e+0], uy = unitb[3*e+1], uz = unitb[3*e+2];
        float r[N_RBF];
        #pragma unroll
        for (int k = 0; k < N_RBF; ++k) r[k] = rbfe[e*N_RBF + k];
        float w0 = b0 * ev, w1 = b1 * ev, w2 = b2 * ev;
        #pragma unroll
        for (int k = 0; k < N_RBF; ++k) {
            float rk = r[k];
            w0 += rk * Wl[k*3*F + tid];
            w1 += rk * Wl[k*3*F + F + tid];
            w2 += rk * Wl[k*3*F + 2*F + tid];
        }
        const float* prow = phi + (size_t)j * 3 * F;
        float s0 = prow[tid] * w0;          // gates old v
        float s1 = prow[tid + F] * w1;      // -> ds
        float s2 = prow[tid + 2*F] * w2;    // -> along unit
        atomicAdd(&s[(size_t)tgt*F + tid], s1);
        float vx = v[(size_t)j*F + tid];
        float vy = v[NF   + (size_t)j*F + tid];
        float vz = v[2*NF + (size_t)j*F + tid];
        atomicAdd(&dv[(size_t)tgt*F + tid],        s2*ux + s0*vx);
        atomicAdd(&dv[NF   + (size_t)tgt*F + tid], s2*uy + s0*vy);
        atomicAdd(&dv[2*NF + (size_t)tgt*F + tid], s2*uz + s0*vz);
    }
}

// ---------------- v += dv ----------------
__global__ __launch_bounds__(256) void vadd_kernel(float* __restrict__ v, const float* __restrict__ dv)
{
    size_t idx = (size_t)blockIdx.x * 256 + threadIdx.x;   // grid sized exactly 3*N*F
    v[idx] += dv[idx];
}

// ---------------- stack = [s | ||v_v||] ----------------
__global__ __launch_bounds__(256) void stack_kernel(
    const float* __restrict__ s, const float* __restrict__ vv, float* __restrict__ stk)
{
    size_t idx = (size_t)blockIdx.x * 256 + threadIdx.x;   // < N*F
    const size_t NF = (size_t)N_ATOMS * F;
    int n = (int)(idx >> 7), f = (int)(idx & 127);
    float x = vv[idx], y = vv[NF + idx], z2 = vv[2*NF + idx];
    float nrm = sqrtf(x*x + y*y + z2*z2 + 1e-15f);
    stk[(size_t)n*2*F + f]     = s[idx];
    stk[(size_t)n*2*F + F + f] = nrm;
}

// ---------------- final conv update: s += <u,v>*a_sv + a_ss ; v += u*a_vv ----------------
__global__ __launch_bounds__(256) void finupd_kernel(
    const float* __restrict__ uv, const float* __restrict__ vv,
    const float* __restrict__ a, float* __restrict__ s, float* __restrict__ v)
{
    size_t idx = (size_t)blockIdx.x * 256 + threadIdx.x;   // < N*F
    const size_t NF = (size_t)N_ATOMS * F;
    int n = (int)(idx >> 7), f = (int)(idx & 127);
    float ux = uv[idx], uy = uv[NF + idx], uz = uv[2*NF + idx];
    float wx = vv[idx], wy = vv[NF + idx], wz = vv[2*NF + idx];
    float dot = ux*wx + uy*wy + uz*wz;
    const float* arow = a + (size_t)n * 3 * F;
    s[idx] += dot * arow[F + f] + arow[2*F + f];
    float avv = arow[f];
    v[idx]        += ux * avv;
    v[NF + idx]   += uy * avv;
    v[2*NF + idx] += uz * avv;
}

// ---------------- readout: atom_e = hr @ ro_w2 + b2 ; energy[mol] += atom_e ----------------
__global__ __launch_bounds__(256) void readout_kernel(
    const float* __restrict__ hr, const float* __restrict__ w2,
    const float* __restrict__ b2, const int* __restrict__ mol, float* __restrict__ out)
{
    int lane = threadIdx.x & 63;
    int n = blockIdx.x * 4 + (threadIdx.x >> 6);   // grid sized exactly N/4
    float val = hr[(size_t)n * 64 + lane] * w2[lane];
    #pragma unroll
    for (int offd = 32; offd > 0; offd >>= 1) val += __shfl_down(val, offd);
    if (lane == 0) atomicAdd(&out[mol[n]], val + b2[0]);
}

extern "C" void kernel_launch(void* const* d_in, const int* in_sizes, int n_in,
                              void* d_out, int out_size, void* d_ws, size_t ws_size,
                              hipStream_t stream)
{
    const float* xyz    = (const float*)d_in[0];
    const float* emb    = (const float*)d_in[1];
    const float* msg_w1 = (const float*)d_in[2];
    const float* msg_b1 = (const float*)d_in[3];
    const float* msg_w2 = (const float*)d_in[4];
    const float* msg_b2 = (const float*)d_in[5];
    const float* rbf_w  = (const float*)d_in[6];
    const float* rbf_b  = (const float*)d_in[7];
    const float* upd_u  = (const float*)d_in[8];
    const float* upd_v  = (const float*)d_in[9];
    const float* upd_w1 = (const float*)d_in[10];
    const float* upd_b1 = (const float*)d_in[11];
    const float* upd_w2 = (const float*)d_in[12];
    const float* upd_b2 = (const float*)d_in[13];
    const float* ro_w1  = (const float*)d_in[14];
    const float* ro_b1  = (const float*)d_in[15];
    const float* ro_w2  = (const float*)d_in[16];
    const float* ro_b2  = (const float*)d_in[17];
    const int*   z      = (const int*)d_in[18];
    const int*   nbrs   = (const int*)d_in[19];
    const int*   molidx = (const int*)d_in[20];
    float* out = (float*)d_out;

    float* ws = (float*)d_ws;
    size_t off = 0;
    auto alloc = [&](size_t n) { float* p = ws + off; off += n; return p; };
    const size_t NF = (size_t)N_ATOMS * F;
    float* s_buf   = alloc(NF);            // s
    float* v_buf   = alloc(3 * NF);        // v: 3 planes [d][n][f]
    float* dv_buf  = alloc(3 * NF);        // message scatter accumulator
    float* uv_buf  = alloc(3 * NF);        // u_v planes
    float* vv_buf  = alloc(3 * NF);        // v_v planes
    float* phi_buf = alloc(3 * NF);        // phi (Nx384), reused as 'a'
    float* h_buf   = alloc(NF);            // MLP hidden / readout hidden
    float* stk_buf = alloc(2 * NF);        // [s | norm]
    float* rbfe    = alloc((size_t)N_EDGES * N_RBF);
    float* envb    = alloc(N_EDGES);
    float* unitb   = alloc((size_t)N_EDGES * 3);
    // total ~23.3M floats = ~93 MB

    hipMemsetAsync(out, 0, sizeof(float) * N_MOLS, stream);
    hipMemsetAsync(v_buf, 0, sizeof(float) * 3 * NF, stream);

    geom_kernel<<<dim3((N_EDGES + 255) / 256), dim3(256), 0, stream>>>(xyz, nbrs, rbfe, envb, unitb);
    embed_kernel<<<dim3((int)(NF / 256)), dim3(256), 0, stream>>>(emb, z, s_buf);

    for (int i = 0; i < 3; ++i) {
        // phi = silu(s@W1+b1)@W2+b2
        gemm_bias_act<<<dim3(F/64, N_ATOMS/64), dim3(256), 0, stream>>>(
            s_buf, msg_w1 + (size_t)i*F*F, msg_b1 + (size_t)i*F, h_buf, N_ATOMS, F, F, 1);
        gemm_bias_act<<<dim3(3*F/64, N_ATOMS/64), dim3(256), 0, stream>>>(
            h_buf, msg_w2 + (size_t)i*F*3*F, msg_b2 + (size_t)i*3*F, phi_buf, N_ATOMS, F, 3*F, 0);
        // message + scatter
        hipMemsetAsync(dv_buf, 0, sizeof(float) * 3 * NF, stream);
        msg_kernel<<<dim3(1280), dim3(128), 0, stream>>>(
            phi_buf, rbfe, envb, unitb, nbrs,
            rbf_w + (size_t)i*N_RBF*3*F, rbf_b + (size_t)i*3*F, v_buf, s_buf, dv_buf);
        vadd_kernel<<<dim3((int)(3*NF/256)), dim3(256), 0, stream>>>(v_buf, dv_buf);
        // u_v / v_v: batched over 3 dims as M=3N GEMM
        gemm_bias_act<<<dim3(F/64, 3*N_ATOMS/64), dim3(256), 0, stream>>>(
            v_buf, upd_u + (size_t)i*F*F, nullptr, uv_buf, 3*N_ATOMS, F, F, 0);
        gemm_bias_act<<<dim3(F/64, 3*N_ATOMS/64), dim3(256), 0, stream>>>(
            v_buf, upd_v + (size_t)i*F*F, nullptr, vv_buf, 3*N_ATOMS, F, F, 0);
        stack_kernel<<<dim3((int)(NF/256)), dim3(256), 0, stream>>>(s_buf, vv_buf, stk_buf);
        // a = silu(stack@W1+b1)@W2+b2   (a lands in phi_buf — phi no longer needed)
        gemm_bias_act<<<dim3(F/64, N_ATOMS/64), dim3(256), 0, stream>>>(
            stk_buf, upd_w1 + (size_t)i*2*F*F, upd_b1 + (size_t)i*F, h_buf, N_ATOMS, 2*F, F, 1);
        gemm_bias_act<<<dim3(3*F/64, N_ATOMS/64), dim3(256), 0, stream>>>(
            h_buf, upd_w2 + (size_t)i*F*3*F, upd_b2 + (size_t)i*3*F, phi_buf, N_ATOMS, F, 3*F, 0);
        finupd_kernel<<<dim3((int)(NF/256)), dim3(256), 0, stream>>>(uv_buf, vv_buf, phi_buf, s_buf, v_buf);
    }

    // readout
    gemm_bias_act<<<dim3(1, N_ATOMS/64), dim3(256), 0, stream>>>(
        s_buf, ro_w1, ro_b1, h_buf, N_ATOMS, F, 64, 1);
    readout_kernel<<<dim3(N_ATOMS/4), dim3(256), 0, stream>>>(h_buf, ro_w2, ro_b2, molidx, out);
}

// Round 2
// 625.725 us; speedup vs baseline: 1.4921x; 1.4921x over previous
//
#include <hip/hip_runtime.h>

static constexpr int F = 128;
static constexpr int N_RBF = 20;
static constexpr int N_ATOMS = 8000;
static constexpr int N_EDGES = 160000;
static constexpr int N_MOLS = 100;
static constexpr float CUTOFF = 5.0f;
#define PIF 3.14159265358979323846f

__device__ __forceinline__ float silu_f(float x) { return x / (1.f + __expf(-x)); }

// ---------------- edge geometry + live-edge histogram ----------------
__global__ __launch_bounds__(256) void geom_kernel(
    const float* __restrict__ xyz, const int* __restrict__ nbrs,
    float* __restrict__ rbfe, float* __restrict__ envb, float* __restrict__ unitb,
    int* __restrict__ cnt)
{
    int e = blockIdx.x * 256 + threadIdx.x;
    if (e >= N_EDGES) return;
    int i0 = nbrs[2*e+0], i1 = nbrs[2*e+1];
    float dx = xyz[3*i1+0] - xyz[3*i0+0];
    float dy = xyz[3*i1+1] - xyz[3*i0+1];
    float dz = xyz[3*i1+2] - xyz[3*i0+2];
    float d  = sqrtf(dx*dx + dy*dy + dz*dz);
    float inv = 1.f / d;
    unitb[3*e+0] = dx*inv; unitb[3*e+1] = dy*inv; unitb[3*e+2] = dz*inv;
    float ev = (d <= CUTOFF) ? 0.5f*(cosf(PIF*d/CUTOFF) + 1.f) : 0.f;
    envb[e] = ev;
    float base = PIF*d/CUTOFF;
    float sc = inv * ev;   // fold env into rbf (w_s = (rbf*env)@W + b*env)
    #pragma unroll
    for (int k = 0; k < N_RBF; ++k)
        rbfe[e*N_RBF + k] = sinf((float)(k+1)*base) * sc;
    if (ev > 0.f) atomicAdd(&cnt[i0], 1);   // live-edge histogram by target
}

// ---------------- exclusive scan of 8000 counters (single block) ----------------
__global__ __launch_bounds__(1024) void scan_kernel(
    const int* __restrict__ cnt, int* __restrict__ offsets)
{
    __shared__ int sums[1024];
    int tid = threadIdx.x;
    int base = tid * 8;
    int local[8]; int s = 0;
    #pragma unroll
    for (int i = 0; i < 8; ++i) {
        int idx = base + i;
        local[i] = (idx < N_ATOMS) ? cnt[idx] : 0;
        s += local[i];
    }
    sums[tid] = s;
    __syncthreads();
    for (int d = 1; d < 1024; d <<= 1) {
        int v = (tid >= d) ? sums[tid - d] : 0;
        __syncthreads();
        sums[tid] += v;
        __syncthreads();
    }
    int ex = (tid == 0) ? 0 : sums[tid - 1];
    #pragma unroll
    for (int i = 0; i < 8; ++i) {
        int idx = base + i;
        if (idx < N_ATOMS) { offsets[idx] = ex; ex += local[i]; }
    }
}

// ---------------- scatter live edge ids into per-atom segments ----------------
__global__ __launch_bounds__(256) void scatter_kernel(
    const int* __restrict__ nbrs, const float* __restrict__ envb,
    const int* __restrict__ offsets, int* __restrict__ cursor,
    int* __restrict__ sorted_eid)
{
    int e = blockIdx.x * 256 + threadIdx.x;
    if (e >= N_EDGES) return;
    if (envb[e] <= 0.f) return;
    int tgt = nbrs[2*e+0];
    int pos = offsets[tgt] + atomicAdd(&cursor[tgt], 1);
    sorted_eid[pos] = e;
}

// ---------------- s = emb_table[z] ----------------
__global__ __launch_bounds__(256) void embed_kernel(
    const float* __restrict__ emb, const int* __restrict__ z, float* __restrict__ s)
{
    int idx = blockIdx.x * 256 + threadIdx.x;   // grid sized exactly N*F
    int n = idx >> 7, f = idx & 127;
    s[idx] = emb[z[n]*F + f];
}

// ---------------- generic f32 GEMM: C = act(A@B + bias) ----------------
// A: MxK row-major, B: KxNc row-major. M%64==0, Nc%64==0, K%16==0 (guaranteed here).
__global__ __launch_bounds__(256) void gemm_bias_act(
    const float* __restrict__ A, const float* __restrict__ B,
    const float* __restrict__ bias, float* __restrict__ C,
    int M, int K, int Nc, int act)
{
    __shared__ float As[16][68];   // [k][m], padded row => 16B-aligned float4 reads
    __shared__ float Bs[16][64];   // [k][n]
    const int tid = threadIdx.x;
    const int tx = tid & 15, ty = tid >> 4;
    const int m0 = blockIdx.y * 64, n0 = blockIdx.x * 64;
    float acc[4][4] = {};
    const int ka = tid & 15;
    const int ma = tid >> 4;
    const int kb = tid >> 4;
    const int cb = (tid & 15) * 4;
    for (int k0 = 0; k0 < K; k0 += 16) {
        #pragma unroll
        for (int r = 0; r < 4; ++r)
            As[ka][ma + 16*r] = A[(size_t)(m0 + ma + 16*r) * K + k0 + ka];
        *(float4*)&Bs[kb][cb] = *(const float4*)&B[(size_t)(k0 + kb) * Nc + n0 + cb];
        __syncthreads();
        #pragma unroll
        for (int kk = 0; kk < 16; ++kk) {
            float4 av = *(const float4*)&As[kk][ty*4];
            float4 bv = *(const float4*)&Bs[kk][tx*4];
            float aa[4] = {av.x, av.y, av.z, av.w};
            float bb[4] = {bv.x, bv.y, bv.z, bv.w};
            #pragma unroll
            for (int i = 0; i < 4; ++i)
                #pragma unroll
                for (int j = 0; j < 4; ++j)
                    acc[i][j] += aa[i] * bb[j];
        }
        __syncthreads();
    }
    float bcol[4];
    #pragma unroll
    for (int j = 0; j < 4; ++j) bcol[j] = bias ? bias[n0 + tx*4 + j] : 0.f;
    #pragma unroll
    for (int i = 0; i < 4; ++i) {
        float4 o;
        o.x = acc[i][0] + bcol[0];
        o.y = acc[i][1] + bcol[1];
        o.z = acc[i][2] + bcol[2];
        o.w = acc[i][3] + bcol[3];
        if (act) { o.x = silu_f(o.x); o.y = silu_f(o.y); o.z = silu_f(o.z); o.w = silu_f(o.w); }
        *(float4*)&C[(size_t)(m0 + ty*4 + i) * Nc + n0 + tx*4] = o;
    }
}

// ---------------- atom-centric message gather ----------------
// One block per target atom; walks its live-edge segment; accumulates ds/dv in
// registers; writes s in-place (only owner touches row n) and v_out = v_in + dv
// (ping-pong: other blocks gather old v[j]). rbf_w columns live in 60 VGPRs.
__global__ __launch_bounds__(128) void msg_gather(
    const float* __restrict__ phi, const float* __restrict__ rbfe,
    const float* __restrict__ envb, const float* __restrict__ unitb,
    const int* __restrict__ nbrs, const float* __restrict__ rbf_w,
    const float* __restrict__ rbf_b, const float* __restrict__ v_in,
    float* __restrict__ s, float* __restrict__ v_out,
    const int* __restrict__ sorted_eid, const int* __restrict__ offsets,
    const int* __restrict__ cnt)
{
    const int n = blockIdx.x, tid = threadIdx.x;
    const size_t NF = (size_t)N_ATOMS * F;
    float W0[N_RBF], W1[N_RBF], W2[N_RBF];
    #pragma unroll
    for (int k = 0; k < N_RBF; ++k) {
        W0[k] = rbf_w[k*3*F + tid];
        W1[k] = rbf_w[k*3*F + F + tid];
        W2[k] = rbf_w[k*3*F + 2*F + tid];
    }
    const float b0 = rbf_b[tid], b1 = rbf_b[F + tid], b2 = rbf_b[2*F + tid];
    float ds = 0.f, dvx = 0.f, dvy = 0.f, dvz = 0.f;
    const int off = offsets[n], c = cnt[n];
    for (int t = 0; t < c; ++t) {
        int e = sorted_eid[off + t];
        int j = nbrs[2*e+1];
        float ev = envb[e];
        float ux = unitb[3*e+0], uy = unitb[3*e+1], uz = unitb[3*e+2];
        float w0 = b0 * ev, w1 = b1 * ev, w2 = b2 * ev;
        #pragma unroll
        for (int k = 0; k < N_RBF; ++k) {
            float rk = rbfe[e*N_RBF + k];
            w0 += rk * W0[k]; w1 += rk * W1[k]; w2 += rk * W2[k];
        }
        const float* prow = phi + (size_t)j * 3 * F;
        float s0 = prow[tid] * w0;
        float s1 = prow[F + tid] * w1;
        float s2 = prow[2*F + tid] * w2;
        ds  += s1;
        dvx += s2*ux + s0 * v_in[(size_t)j*F + tid];
        dvy += s2*uy + s0 * v_in[NF   + (size_t)j*F + tid];
        dvz += s2*uz + s0 * v_in[2*NF + (size_t)j*F + tid];
    }
    size_t idx = (size_t)n * F + tid;
    s[idx] += ds;
    v_out[idx]        = v_in[idx]        + dvx;
    v_out[NF + idx]   = v_in[NF + idx]   + dvy;
    v_out[2*NF + idx] = v_in[2*NF + idx] + dvz;
}

// ---------------- stack = [s | ||v_v||] ----------------
__global__ __launch_bounds__(256) void stack_kernel(
    const float* __restrict__ s, const float* __restrict__ vv, float* __restrict__ stk)
{
    size_t idx = (size_t)blockIdx.x * 256 + threadIdx.x;   // < N*F
    const size_t NF = (size_t)N_ATOMS * F;
    int n = (int)(idx >> 7), f = (int)(idx & 127);
    float x = vv[idx], y = vv[NF + idx], z2 = vv[2*NF + idx];
    float nrm = sqrtf(x*x + y*y + z2*z2 + 1e-15f);
    stk[(size_t)n*2*F + f]     = s[idx];
    stk[(size_t)n*2*F + F + f] = nrm;
}

// ---------------- final conv update: s += <u,v>*a_sv + a_ss ; v += u*a_vv ----------------
__global__ __launch_bounds__(256) void finupd_kernel(
    const float* __restrict__ uv, const float* __restrict__ vv,
    const float* __restrict__ a, float* __restrict__ s, float* __restrict__ v)
{
    size_t idx = (size_t)blockIdx.x * 256 + threadIdx.x;   // < N*F
    const size_t NF = (size_t)N_ATOMS * F;
    int n = (int)(idx >> 7), f = (int)(idx & 127);
    float ux = uv[idx], uy = uv[NF + idx], uz = uv[2*NF + idx];
    float wx = vv[idx], wy = vv[NF + idx], wz = vv[2*NF + idx];
    float dot = ux*wx + uy*wy + uz*wz;
    const float* arow = a + (size_t)n * 3 * F;
    s[idx] += dot * arow[F + f] + arow[2*F + f];
    float avv = arow[f];
    v[idx]        += ux * avv;
    v[NF + idx]   += uy * avv;
    v[2*NF + idx] += uz * avv;
}

// ---------------- readout: atom_e = hr @ ro_w2 + b2 ; energy[mol] += atom_e ----------------
__global__ __launch_bounds__(256) void readout_kernel(
    const float* __restrict__ hr, const float* __restrict__ w2,
    const float* __restrict__ b2, const int* __restrict__ mol, float* __restrict__ out)
{
    int lane = threadIdx.x & 63;
    int n = blockIdx.x * 4 + (threadIdx.x >> 6);   // grid sized exactly N/4
    float val = hr[(size_t)n * 64 + lane] * w2[lane];
    #pragma unroll
    for (int offd = 32; offd > 0; offd >>= 1) val += __shfl_down(val, offd);
    if (lane == 0) atomicAdd(&out[mol[n]], val + b2[0]);
}

extern "C" void kernel_launch(void* const* d_in, const int* in_sizes, int n_in,
                              void* d_out, int out_size, void* d_ws, size_t ws_size,
                              hipStream_t stream)
{
    const float* xyz    = (const float*)d_in[0];
    const float* emb    = (const float*)d_in[1];
    const float* msg_w1 = (const float*)d_in[2];
    const float* msg_b1 = (const float*)d_in[3];
    const float* msg_w2 = (const float*)d_in[4];
    const float* msg_b2 = (const float*)d_in[5];
    const float* rbf_w  = (const float*)d_in[6];
    const float* rbf_b  = (const float*)d_in[7];
    const float* upd_u  = (const float*)d_in[8];
    const float* upd_v  = (const float*)d_in[9];
    const float* upd_w1 = (const float*)d_in[10];
    const float* upd_b1 = (const float*)d_in[11];
    const float* upd_w2 = (const float*)d_in[12];
    const float* upd_b2 = (const float*)d_in[13];
    const float* ro_w1  = (const float*)d_in[14];
    const float* ro_b1  = (const float*)d_in[15];
    const float* ro_w2  = (const float*)d_in[16];
    const float* ro_b2  = (const float*)d_in[17];
    const int*   z      = (const int*)d_in[18];
    const int*   nbrs   = (const int*)d_in[19];
    const int*   molidx = (const int*)d_in[20];
    float* out = (float*)d_out;

    float* ws = (float*)d_ws;
    size_t off = 0;
    auto alloc = [&](size_t n) { float* p = ws + off; off += n; return p; };
    const size_t NF = (size_t)N_ATOMS * F;
    float* s_buf   = alloc(NF);            // s (updated in-place)
    float* v1_buf  = alloc(3 * NF);        // v ping
    float* v2_buf  = alloc(3 * NF);        // v pong
    float* uv_buf  = alloc(3 * NF);        // u_v planes
    float* vv_buf  = alloc(3 * NF);        // v_v planes
    float* phi_buf = alloc(3 * NF);        // phi (Nx384), reused as 'a'
    float* h_buf   = alloc(NF);            // MLP hidden / readout hidden
    float* stk_buf = alloc(2 * NF);        // [s | norm]
    float* rbfe    = alloc((size_t)N_EDGES * N_RBF);
    float* envb    = alloc(N_EDGES);
    float* unitb   = alloc((size_t)N_EDGES * 3);
    int* cnt        = (int*)alloc(N_ATOMS);
    int* cursor     = (int*)alloc(N_ATOMS);
    int* offsets    = (int*)alloc(N_ATOMS);
    int* sorted_eid = (int*)alloc(N_EDGES);
    // total ~22.5M floats = ~90 MB

    hipMemsetAsync(out, 0, sizeof(float) * N_MOLS, stream);
    hipMemsetAsync(v1_buf, 0, sizeof(float) * 3 * NF, stream);
    hipMemsetAsync(cnt, 0, sizeof(int) * 2 * N_ATOMS, stream);   // cnt + cursor adjacent

    geom_kernel<<<dim3((N_EDGES + 255) / 256), dim3(256), 0, stream>>>(
        xyz, nbrs, rbfe, envb, unitb, cnt);
    scan_kernel<<<dim3(1), dim3(1024), 0, stream>>>(cnt, offsets);
    scatter_kernel<<<dim3((N_EDGES + 255) / 256), dim3(256), 0, stream>>>(
        nbrs, envb, offsets, cursor, sorted_eid);
    embed_kernel<<<dim3((int)(NF / 256)), dim3(256), 0, stream>>>(emb, z, s_buf);

    float* vin = v1_buf;
    float* vout = v2_buf;
    for (int i = 0; i < 3; ++i) {
        // phi = silu(s@W1+b1)@W2+b2
        gemm_bias_act<<<dim3(F/64, N_ATOMS/64), dim3(256), 0, stream>>>(
            s_buf, msg_w1 + (size_t)i*F*F, msg_b1 + (size_t)i*F, h_buf, N_ATOMS, F, F, 1);
        gemm_bias_act<<<dim3(3*F/64, N_ATOMS/64), dim3(256), 0, stream>>>(
            h_buf, msg_w2 + (size_t)i*F*3*F, msg_b2 + (size_t)i*3*F, phi_buf, N_ATOMS, F, 3*F, 0);
        // atomic-free message gather: s += ds in place; vout = vin + dv
        msg_gather<<<dim3(N_ATOMS), dim3(128), 0, stream>>>(
            phi_buf, rbfe, envb, unitb, nbrs,
            rbf_w + (size_t)i*N_RBF*3*F, rbf_b + (size_t)i*3*F,
            vin, s_buf, vout, sorted_eid, offsets, cnt);
        // u_v / v_v: batched over 3 dims as M=3N GEMM
        gemm_bias_act<<<dim3(F/64, 3*N_ATOMS/64), dim3(256), 0, stream>>>(
            vout, upd_u + (size_t)i*F*F, nullptr, uv_buf, 3*N_ATOMS, F, F, 0);
        gemm_bias_act<<<dim3(F/64, 3*N_ATOMS/64), dim3(256), 0, stream>>>(
            vout, upd_v + (size_t)i*F*F, nullptr, vv_buf, 3*N_ATOMS, F, F, 0);
        stack_kernel<<<dim3((int)(NF/256)), dim3(256), 0, stream>>>(s_buf, vv_buf, stk_buf);
        // a = silu(stack@W1+b1)@W2+b2   (a lands in phi_buf — phi no longer needed)
        gemm_bias_act<<<dim3(F/64, N_ATOMS/64), dim3(256), 0, stream>>>(
            stk_buf, upd_w1 + (size_t)i*2*F*F, upd_b1 + (size_t)i*F, h_buf, N_ATOMS, 2*F, F, 1);
        gemm_bias_act<<<dim3(3*F/64, N_ATOMS/64), dim3(256), 0, stream>>>(
            h_buf, upd_w2 + (size_t)i*F*3*F, upd_b2 + (size_t)i*3*F, phi_buf, N_ATOMS, F, 3*F, 0);
        finupd_kernel<<<dim3((int)(NF/256)), dim3(256), 0, stream>>>(
            uv_buf, vv_buf, phi_buf, s_buf, vout);
        float* tmp = vin; vin = vout; vout = tmp;
    }

    // readout
    gemm_bias_act<<<dim3(1, N_ATOMS/64), dim3(256), 0, stream>>>(
        s_buf, ro_w1, ro_b1, h_buf, N_ATOMS, F, 64, 1);
    readout_kernel<<<dim3(N_ATOMS/4), dim3(256), 0, stream>>>(h_buf, ro_w2, ro_b2, molidx, out);
}